// Round 1
// baseline (63.232 us; speedup 1.0000x reference)
//
#include <hip/hip_runtime.h>
#include <hip/hip_bf16.h>
#include <float.h>

#define EPSV 1e-6f
#define TGT_TILE 4096   // float2 per LDS tile (32 KB)

// Directed Hausdorff (squared): for each src point j, m2[j] = min_i ||src_j - tgt_i + eps||^2.
// Block-reduce max over j, atomicMax into ws[b] (uint bit-pattern of nonneg float).
// grid: x = ceil(Lmax/256), y = batch, z = direction (0: src=c2,tgt=c1 ; 1: src=c1,tgt=c2)
__global__ __launch_bounds__(256) void hausdorff_directed_kernel(
    const float* __restrict__ c1, const float* __restrict__ c2,
    unsigned int* __restrict__ ws, int L1, int L2) {
    const int b   = blockIdx.y;
    const int dir = blockIdx.z;

    const float* src;
    const float* tgt;
    int Lsrc, Ltgt;
    if (dir == 0) { src = c2 + (size_t)b * L2 * 2; tgt = c1 + (size_t)b * L1 * 2; Lsrc = L2; Ltgt = L1; }
    else          { src = c1 + (size_t)b * L1 * 2; tgt = c2 + (size_t)b * L2 * 2; Lsrc = L1; Ltgt = L2; }

    __shared__ float2 t_lds[TGT_TILE];
    __shared__ float red[4];

    const int j = blockIdx.x * 256 + threadIdx.x;
    const bool active = (j < Lsrc);

    float sx = 0.f, sy = 0.f;
    if (active) {
        float2 s = ((const float2*)src)[j];
        sx = s.x + EPSV;   // diff = src - tgt + eps  ->  (src+eps) - tgt
        sy = s.y + EPSV;
    }

    float m0 = FLT_MAX, m1 = FLT_MAX, m2 = FLT_MAX, m3 = FLT_MAX;

    for (int base = 0; base < Ltgt; base += TGT_TILE) {
        const int chunk = min(TGT_TILE, Ltgt - base);
        // cooperative stage of target tile into LDS
        for (int k = threadIdx.x; k < chunk; k += 256) {
            t_lds[k] = ((const float2*)tgt)[base + k];
        }
        __syncthreads();

        int i = 0;
        const int lim = chunk & ~3;
        #pragma unroll 4
        for (; i < lim; i += 4) {
            float2 t0 = t_lds[i + 0];
            float2 t1 = t_lds[i + 1];
            float2 t2 = t_lds[i + 2];
            float2 t3 = t_lds[i + 3];
            float dx0 = sx - t0.x, dy0 = sy - t0.y;
            float dx1 = sx - t1.x, dy1 = sy - t1.y;
            float dx2 = sx - t2.x, dy2 = sy - t2.y;
            float dx3 = sx - t3.x, dy3 = sy - t3.y;
            float d0 = fmaf(dy0, dy0, dx0 * dx0);
            float d1 = fmaf(dy1, dy1, dx1 * dx1);
            float d2 = fmaf(dy2, dy2, dx2 * dx2);
            float d3 = fmaf(dy3, dy3, dx3 * dx3);
            m0 = fminf(m0, d0);
            m1 = fminf(m1, d1);
            m2 = fminf(m2, d2);
            m3 = fminf(m3, d3);
        }
        for (; i < chunk; ++i) {
            float2 t0 = t_lds[i];
            float dx0 = sx - t0.x, dy0 = sy - t0.y;
            m0 = fminf(m0, fmaf(dy0, dy0, dx0 * dx0));
        }
        __syncthreads();
    }

    float m = fminf(fminf(m0, m1), fminf(m2, m3));
    if (!active) m = 0.0f;   // neutral for the max-reduce (all true values >= 0)

    // wave (64-lane) max reduce
    for (int off = 32; off > 0; off >>= 1)
        m = fmaxf(m, __shfl_down(m, off));

    if ((threadIdx.x & 63) == 0) red[threadIdx.x >> 6] = m;
    __syncthreads();
    if (threadIdx.x == 0) {
        float r = fmaxf(fmaxf(red[0], red[1]), fmaxf(red[2], red[3]));
        atomicMax(&ws[b], __float_as_uint(r));
    }
}

__global__ void hausdorff_finalize_kernel(const unsigned int* __restrict__ ws,
                                          const float* __restrict__ res,
                                          float* __restrict__ out, int B) {
    int t = threadIdx.x;
    if (t < B) {
        out[t] = sqrtf(__uint_as_float(ws[t])) * res[t];
    }
}

extern "C" void kernel_launch(void* const* d_in, const int* in_sizes, int n_in,
                              void* d_out, int out_size, void* d_ws, size_t ws_size,
                              hipStream_t stream) {
    const float* c1  = (const float*)d_in[0];
    const float* c2  = (const float*)d_in[1];
    const float* res = (const float*)d_in[2];
    float* out = (float*)d_out;

    const int B  = in_sizes[2];
    const int L1 = in_sizes[0] / (B * 2);
    const int L2 = in_sizes[1] / (B * 2);

    unsigned int* ws = (unsigned int*)d_ws;

    // zero the per-batch running max (bit pattern 0 == 0.0f)
    hipMemsetAsync(ws, 0, (size_t)B * sizeof(unsigned int), stream);

    const int Lmax = max(L1, L2);
    dim3 grid((Lmax + 255) / 256, B, 2);
    hipLaunchKernelGGL(hausdorff_directed_kernel, grid, dim3(256), 0, stream,
                       c1, c2, ws, L1, L2);

    hipLaunchKernelGGL(hausdorff_finalize_kernel, dim3(1), dim3(64), 0, stream,
                       ws, res, out, B);
}